// Round 8
// baseline (2270.136 us; speedup 1.0000x reference)
//
#include <hip/hip_runtime.h>

// LSTM: B=512, T=1024, D=64, H=128, gates=4H=512, fc head H->64->1.
//
// Round 7 post-mortem: (a) VGPR_Count=52 proves the PRE-LOOP asm pin did not
// keep the 48 B-fragment VGPRs resident -- the weight-build chain re-ran
// every step from L2 (~4500 cyc/step). Fix: pin each fragment with
// asm volatile "+v" INSIDE the t-loop (loop-carried asm outputs cannot be
// rematerialized or sunk). (b) 16 waves saturated the LDS pipe (~2900
// cyc/step of issue). Fix: 8 waves x 4 N-tiles (same MFMA count, half the
// A-frag reads) and ALL gate traffic as b128: D-tile stored TRANSPOSED
// (gl[gate][row]; acc[0..3] = 4 consecutive rows = one ds_write_b128) and
// the cell reads 4 rows per gate as one b128. (c) bias folded into acc init.
//
// 32 blocks x 512 threads (8 waves), block owns 16 batch rows.
// Per step: gates[16,512] = [h|x][16,192] @ W^T via v_mfma_f32_16x16x32_f16.
// Wave w owns gates [64w,64w+64) = 4 N-tiles x 6 K-tiles = 24 MFMA/step.
// Cell: thread (u = tid&127, qd = tid>>7) owns unit u, rows 4qd..4qd+3,
// c[4] in registers. 2 barriers/step.

#define TT 1024
#define DD 64
#define HH 128
#define ROWS 16
#define PROW 200    // hx row stride in f16 (400 B, 16B-aligned)
#define GROW 20     // gl row stride in f32 (16 rows + 4 pad)

typedef _Float16 f16x8 __attribute__((ext_vector_type(8)));
typedef float f32x4 __attribute__((ext_vector_type(4)));

__device__ __forceinline__ float sigm(float x) {
    return 1.f / (1.f + __expf(-x));
}
__device__ __forceinline__ float tanh_f(float x) {
    return 1.f - 2.f / (__expf(2.f * x) + 1.f);
}

__global__ __launch_bounds__(512, 1)
void lstm_mfma_kernel(const float* __restrict__ x_seq,
                      const float* __restrict__ W_ih,
                      const float* __restrict__ W_hh,
                      const float* __restrict__ b_ih,
                      const float* __restrict__ b_hh,
                      const float* __restrict__ W1v,
                      const float* __restrict__ b1v,
                      const float* __restrict__ W2v,
                      const float* __restrict__ b2v,
                      float* __restrict__ out)
{
    const int tid  = threadIdx.x;
    const int lane = tid & 63;
    const int w    = tid >> 6;        // wave 0..7
    const int p    = lane >> 4;       // k-group 0..3
    const int cc   = lane & 15;       // col (B/D) / row (A) within tile
    const int b0   = blockIdx.x * ROWS;

    __shared__ __align__(16) _Float16 hx[2][ROWS][PROW];  // [buf][row][h|x]
    __shared__ __align__(16) float    gl[512][GROW];      // [gate][row] f32

    // ---- B-fragments: wave w owns gates [64w,64w+64), 4 N-tiles x 6 K ----
    // frag(nt,g): lane holds W[gate=64w+16nt+cc][k=32g+8p+j], j=0..7
    f16x8 bf[4][6];
    float bias[4];
#pragma unroll
    for (int nt = 0; nt < 4; ++nt) {
        const int gate = 64 * w + 16 * nt + cc;
        bias[nt] = b_ih[gate] + b_hh[gate];
#pragma unroll
        for (int g = 0; g < 6; ++g) {
            f16x8 f;
#pragma unroll
            for (int j = 0; j < 8; ++j) {
                const int k = 32 * g + 8 * p + j;
                const float v = (k < HH) ? W_hh[gate * HH + k]
                                         : W_ih[gate * DD + (k - HH)];
                f[j] = (_Float16)v;
            }
            bf[nt][g] = f;
        }
    }

    // ---- cell ownership: unit u, rows 4qd..4qd+3 ----
    const int u  = tid & 127;
    const int qd = tid >> 7;
    float c0 = 0.f, c1 = 0.f, c2 = 0.f, c3 = 0.f;

    // ---- init: h = 0 (2048 cells), x(0) (1024 elems) ----
#pragma unroll
    for (int i = 0; i < 4; ++i) {
        const int idx = tid + 512 * i;
        hx[0][idx >> 7][idx & 127] = (_Float16)0.f;
    }
    {
        const int xr = tid >> 6, xk = tid & 63;
        hx[0][xr][HH + xk]     = (_Float16)x_seq[((b0 + xr) * TT) * DD + xk];
        hx[0][xr + 8][HH + xk] = (_Float16)x_seq[((b0 + xr + 8) * TT) * DD + xk];
    }
    __syncthreads();

    const int xr = tid >> 6, xk = tid & 63;   // x-prefetch coords

    for (int t = 0; t < TT; ++t) {
        const int cur = t & 1, nxt = cur ^ 1;

        // prefetch x(t+1) early (coalesced); hides under the MFMA phase
        float xp0 = 0.f, xp1 = 0.f;
        const bool pre = (t + 1 < TT);
        if (pre) {
            xp0 = x_seq[((b0 + xr) * TT + (t + 1)) * DD + xk];
            xp1 = x_seq[((b0 + xr + 8) * TT + (t + 1)) * DD + xk];
        }

        // ---- A-fragments: row cc, k-slice 32g+8p (shared by 4 N-tiles) ----
        f16x8 a[6];
#pragma unroll
        for (int g = 0; g < 6; ++g)
            a[g] = *reinterpret_cast<const f16x8*>(&hx[cur][cc][32 * g + 8 * p]);

        // ---- 4 interleaved MFMA chains, bias folded into acc init ----
        f32x4 acc[4];
#pragma unroll
        for (int nt = 0; nt < 4; ++nt)
            acc[nt] = (f32x4){bias[nt], bias[nt], bias[nt], bias[nt]};
#pragma unroll
        for (int g = 0; g < 6; ++g)
#pragma unroll
            for (int nt = 0; nt < 4; ++nt)
                acc[nt] = __builtin_amdgcn_mfma_f32_16x16x32_f16(
                    a[g], bf[nt][g], acc[nt], 0, 0, 0);

        // ---- transposed store: acc[j] = row 4p+j of gate 64w+16nt+cc ----
#pragma unroll
        for (int nt = 0; nt < 4; ++nt)
            *reinterpret_cast<f32x4*>(&gl[64 * w + 16 * nt + cc][4 * p]) =
                acc[nt];
        __syncthreads();

        // ---- cell: unit u, rows 4qd..4qd+3, one b128 per gate class ----
        {
            const f32x4 gi = *reinterpret_cast<const f32x4*>(&gl[u][4 * qd]);
            const f32x4 gf =
                *reinterpret_cast<const f32x4*>(&gl[u + 128][4 * qd]);
            const f32x4 gg =
                *reinterpret_cast<const f32x4*>(&gl[u + 256][4 * qd]);
            const f32x4 go =
                *reinterpret_cast<const f32x4*>(&gl[u + 384][4 * qd]);

            c0 = sigm(gf[0]) * c0 + sigm(gi[0]) * tanh_f(gg[0]);
            c1 = sigm(gf[1]) * c1 + sigm(gi[1]) * tanh_f(gg[1]);
            c2 = sigm(gf[2]) * c2 + sigm(gi[2]) * tanh_f(gg[2]);
            c3 = sigm(gf[3]) * c3 + sigm(gi[3]) * tanh_f(gg[3]);
            hx[nxt][4 * qd + 0][u] = (_Float16)(sigm(go[0]) * tanh_f(c0));
            hx[nxt][4 * qd + 1][u] = (_Float16)(sigm(go[1]) * tanh_f(c1));
            hx[nxt][4 * qd + 2][u] = (_Float16)(sigm(go[2]) * tanh_f(c2));
            hx[nxt][4 * qd + 3][u] = (_Float16)(sigm(go[3]) * tanh_f(c3));
        }
        if (pre) {
            hx[nxt][xr][HH + xk]     = (_Float16)xp0;
            hx[nxt][xr + 8][HH + xk] = (_Float16)xp1;
        }
        __syncthreads();

        // ---- THE FIX: loop-carried pins -- weights cannot be remat'd ----
#pragma unroll
        for (int nt = 0; nt < 4; ++nt) {
#pragma unroll
            for (int g = 0; g < 6; ++g)
                asm volatile("" : "+v"(bf[nt][g]));
            asm volatile("" : "+v"(bias[nt]));
        }
    }

    // ---- fused head: wave w -> rows 2w, 2w+1; lane = fc1 unit ----
#pragma unroll
    for (int rr = 0; rr < 2; ++rr) {
        const int r = 2 * w + rr;
        float z = b1v[lane];
        const float* w1 = W1v + lane * HH;
#pragma unroll 16
        for (int k = 0; k < HH; ++k)
            z = fmaf(w1[k], (float)hx[0][r][k], z);
        z = fmaxf(z, 0.f) * W2v[lane];
#pragma unroll
        for (int off = 32; off; off >>= 1)
            z += __shfl_down(z, off, 64);
        if (lane == 0) out[b0 + r] = z + b2v[0];
    }
}

extern "C" void kernel_launch(void* const* d_in, const int* in_sizes, int n_in,
                              void* d_out, int out_size, void* d_ws, size_t ws_size,
                              hipStream_t stream) {
    const float* x_seq = (const float*)d_in[0];
    const float* W_ih  = (const float*)d_in[1];
    const float* W_hh  = (const float*)d_in[2];
    const float* b_ih  = (const float*)d_in[3];
    const float* b_hh  = (const float*)d_in[4];
    const float* W1    = (const float*)d_in[5];
    const float* b1    = (const float*)d_in[6];
    const float* W2    = (const float*)d_in[7];
    const float* b2    = (const float*)d_in[8];
    float* out = (float*)d_out;

    lstm_mfma_kernel<<<32, 512, 0, stream>>>(
        x_seq, W_ih, W_hh, b_ih, b_hh, W1, b1, W2, b2, out);
}